// Round 2
// baseline (60.058 us; speedup 1.0000x reference)
//
#include <hip/hip_runtime.h>
#include <hip/hip_bf16.h>

// Additive attention weights: B=2,H=4,LQ=LKV=512,D=64, fp32 in/out.
//   tanh(x) = 1 - 2/(1+e^{2x});  softmax drops uniform shift (sum w + b_logit)
//   => effective logit = sum_e (-2 w_e) * 1/(1 + exp2((qp+kp+b)*2*log2e))
// Kernel A precomputes qs=(qp+b_concat)*2log2e, ks=kp*2log2e into d_ws.

#define NQROWS 4096   // B*H*LQ

__device__ __forceinline__ float sig2(float x) {
  // 1 / (1 + exp2(x))
  const float u = __builtin_amdgcn_exp2f(x);
  return __builtin_amdgcn_rcpf(1.0f + u);
}

// ---------------- kernel A: projections ----------------
__global__ __launch_bounds__(256) void proj_kernel(
    const float* __restrict__ Q, const float* __restrict__ K,
    const float* __restrict__ W, const float* __restrict__ bC,
    float* __restrict__ qs, float* __restrict__ ks)
{
  const int t  = threadIdx.x;
  const int tr = t >> 6;        // 0..3
  const int e  = t & 63;
  const int rbase = blockIdx.x * 16;
  const bool isK = rbase >= NQROWS;
  const int r0 = isK ? rbase - NQROWS : rbase;
  const float* __restrict__ src = isK ? K : Q;
  const int off = isK ? 64 : 0;

  __shared__ float  srow[16][64];    // 4KB, broadcast reads
  __shared__ float4 wsh[64][16];     // 16KB, XOR-swizzled (f4 col ^ (row&7))

  for (int i = t; i < 16 * 64; i += 256)
    srow[i >> 6][i & 63] = src[(r0 + (i >> 6)) * 64 + (i & 63)];
  for (int i = t; i < 64 * 16; i += 256) {
    const int er = i >> 4, d4 = i & 15;
    wsh[er][d4 ^ (er & 7)] =
        reinterpret_cast<const float4*>(W + er * 128 + off)[d4];
  }
  __syncthreads();

  float acc0 = 0.f, acc1 = 0.f, acc2 = 0.f, acc3 = 0.f;
  const int rA = tr * 4;
  #pragma unroll
  for (int d4 = 0; d4 < 16; ++d4) {
    const float4 w4 = wsh[e][d4 ^ (e & 7)];
    const float4 s0 = *reinterpret_cast<const float4*>(&srow[rA + 0][d4 * 4]);
    const float4 s1 = *reinterpret_cast<const float4*>(&srow[rA + 1][d4 * 4]);
    const float4 s2 = *reinterpret_cast<const float4*>(&srow[rA + 2][d4 * 4]);
    const float4 s3 = *reinterpret_cast<const float4*>(&srow[rA + 3][d4 * 4]);
    acc0 = fmaf(s0.x, w4.x, acc0); acc0 = fmaf(s0.y, w4.y, acc0);
    acc0 = fmaf(s0.z, w4.z, acc0); acc0 = fmaf(s0.w, w4.w, acc0);
    acc1 = fmaf(s1.x, w4.x, acc1); acc1 = fmaf(s1.y, w4.y, acc1);
    acc1 = fmaf(s1.z, w4.z, acc1); acc1 = fmaf(s1.w, w4.w, acc1);
    acc2 = fmaf(s2.x, w4.x, acc2); acc2 = fmaf(s2.y, w4.y, acc2);
    acc2 = fmaf(s2.z, w4.z, acc2); acc2 = fmaf(s2.w, w4.w, acc2);
    acc3 = fmaf(s3.x, w4.x, acc3); acc3 = fmaf(s3.y, w4.y, acc3);
    acc3 = fmaf(s3.z, w4.z, acc3); acc3 = fmaf(s3.w, w4.w, acc3);
  }

  const float C2 = 2.8853900817779268f;   // 2*log2(e)
  const float bias = isK ? 0.0f : bC[e];
  float* __restrict__ dst = isK ? ks : qs;
  dst[(r0 + rA + 0) * 64 + e] = (acc0 + bias) * C2;
  dst[(r0 + rA + 1) * 64 + e] = (acc1 + bias) * C2;
  dst[(r0 + rA + 2) * 64 + e] = (acc2 + bias) * C2;
  dst[(r0 + rA + 3) * 64 + e] = (acc3 + bias) * C2;
}

// ---------------- kernel B: fused logits + masked softmax ----------------
// Grid: 1024 blocks (bh 0..7 x qblk 0..127), 256 threads = 4 waves.
// Each WAVE owns one q-row; lane tk covers k = tile*128 + jj*64 + tk.
// K-tile (128 rows x 64 e) staged in 32KB LDS; async-stage split (T14):
// next tile's global loads issued before compute, ds_write after barrier.
__global__ __launch_bounds__(256) void attn_kernel(
    const float* __restrict__ qs, const float* __restrict__ ks,
    const float* __restrict__ wl, const int* __restrict__ mask,
    float* __restrict__ out)
{
  const int t   = threadIdx.x;
  const int w   = t >> 6;        // wave 0..3
  const int tk  = t & 63;
  const int blk = blockIdx.x;
  const int bh  = blk >> 7;      // 0..7
  const int qb  = blk & 127;     // 0..127
  const int b   = bh >> 2;       // H=4
  const int q   = qb * 4 + w;    // this wave's q row (0..511)

  __shared__ float4 kp4[128][16];   // 32KB, XOR-swizzled (f4 col ^ (row&7))
  __shared__ float  qsh[4][64];
  __shared__ float  w2s[64];

  if (t < 64) w2s[t] = -2.0f * wl[t];
  qsh[w][tk] = qs[(bh * 512 + qb * 4 + w) * 64 + tk];

  const float* __restrict__ kbase = ks + bh * 512 * 64;

  float4 sreg[8];
  // stage-issue: iteration it covers idx=t+it*256; row=idx>>4, e4=idx&15
  #define ISSUE(tile)                                                         \
    _Pragma("unroll")                                                         \
    for (int it = 0; it < 8; ++it) {                                          \
      const int idx = t + it * 256;                                           \
      sreg[it] = reinterpret_cast<const float4*>(                             \
          kbase + ((tile) * 128 + (idx >> 4)) * 64)[idx & 15];                \
    }
  #define WRITE()                                                             \
    _Pragma("unroll")                                                         \
    for (int it = 0; it < 8; ++it) {                                          \
      const int idx = t + it * 256;                                           \
      kp4[idx >> 4][(idx & 15) ^ ((idx >> 4) & 7)] = sreg[it];                \
    }

  float acc[8];
  #pragma unroll
  for (int j = 0; j < 8; ++j) acc[j] = 0.f;

  ISSUE(0);
  WRITE();
  __syncthreads();

  #pragma unroll
  for (int tile = 0; tile < 4; ++tile) {
    if (tile < 3) { ISSUE(tile + 1); }   // overlap L2 latency with compute
    #pragma unroll
    for (int e4 = 0; e4 < 16; ++e4) {
      const float4 qa = *reinterpret_cast<const float4*>(&qsh[w][e4 * 4]);
      const float4 w4 = *reinterpret_cast<const float4*>(&w2s[e4 * 4]);
      #pragma unroll
      for (int jj = 0; jj < 2; ++jj) {
        const int kk = jj * 64 + tk;
        const float4 kv = kp4[kk][e4 ^ (kk & 7)];
        float a = acc[tile * 2 + jj];
        a = fmaf(w4.x, sig2(qa.x + kv.x), a);
        a = fmaf(w4.y, sig2(qa.y + kv.y), a);
        a = fmaf(w4.z, sig2(qa.z + kv.z), a);
        a = fmaf(w4.w, sig2(qa.w + kv.w), a);
        acc[tile * 2 + jj] = a;
      }
    }
    __syncthreads();
    if (tile < 3) { WRITE(); __syncthreads(); }
  }

  // ---- mask + softmax (one row per wave: full-wave shfl) ----
  const int* __restrict__ mrow = mask + (b * 512 + q) * 512;
  int mv[8];
  #pragma unroll
  for (int j = 0; j < 8; ++j)
    mv[j] = mrow[(j >> 1) * 128 + (j & 1) * 64 + tk];
  int lo = 0;
  #pragma unroll
  for (int j = 0; j < 8; ++j) lo |= mv[j];
  const bool rowany = __any(lo != 0);
  const float NEG = -__builtin_inff();
  #pragma unroll
  for (int j = 0; j < 8; ++j)
    if (rowany && mv[j] == 0) acc[j] = NEG;

  float m = acc[0];
  #pragma unroll
  for (int j = 1; j < 8; ++j) m = fmaxf(m, acc[j]);
  #pragma unroll
  for (int s = 1; s < 64; s <<= 1) m = fmaxf(m, __shfl_xor(m, s));

  const float L2E = 1.4426950408889634f;
  const float c = m * L2E;
  float p[8];
  float sum = 0.f;
  #pragma unroll
  for (int j = 0; j < 8; ++j) {
    p[j] = __builtin_amdgcn_exp2f(fmaf(acc[j], L2E, -c));
    sum += p[j];
  }
  #pragma unroll
  for (int s = 1; s < 64; s <<= 1) sum += __shfl_xor(sum, s);
  const float inv = 1.0f / sum;

  float* __restrict__ o = out + (bh * 512 + q) * 512;
  #pragma unroll
  for (int j = 0; j < 8; ++j)
    o[(j >> 1) * 128 + (j & 1) * 64 + tk] = p[j] * inv;
}

extern "C" void kernel_launch(void* const* d_in, const int* in_sizes, int n_in,
                              void* d_out, int out_size, void* d_ws, size_t ws_size,
                              hipStream_t stream) {
  const float* Q  = (const float*)d_in[0];
  const float* K  = (const float*)d_in[1];
  // d_in[2] = values : unused by the reference output
  const int*   M  = (const int*)d_in[3];
  const float* W  = (const float*)d_in[4];
  const float* bC = (const float*)d_in[5];
  const float* wl = (const float*)d_in[6];
  // d_in[7] = b_logit : uniform shift, cancels in softmax
  float* out = (float*)d_out;
  float* qs = (float*)d_ws;            // 4096*64 floats = 1MB
  float* ks = qs + NQROWS * 64;        // 1MB

  proj_kernel<<<512, 256, 0, stream>>>(Q, K, W, bC, qs, ks);
  attn_kernel<<<1024, 256, 0, stream>>>(qs, ks, wl, M, out);
}